// Round 2
// baseline (403.497 us; speedup 1.0000x reference)
//
#include <hip/hip_runtime.h>

// dijetReinforceLayer via MFMA, R4: direct gather + depth-2 load pipeline.
// out[n,o,s] = b[o] + sum_{c,j} W[o,c,j] * din[n,c,s,j],
//   din[...,0..1] = x[n,c,2s..2s+1], din[...,2] = d[n,c,s].
// GEMM view: out[o, col] = sum_k A[o,k] B[k,col], col=(n,s), K=96.
// K reorder: k = 2c+j for j in {0,1} (x part), k = 64+c for j=2 (d part).
//
// R4 theory: R3 (direct gather, VGPR=60) was ILP-starved: Little's law at
// 1.77 TB/s & ~900cy latency => ~2 loads in flight per wave. The compiler,
// squeezed to 60 VGPRs, serialized each col-tile: load -> vmcnt(0) -> pack
// -> mfma. Fix: explicit depth-2 pipeline over col-tiles with named register
// buffers (static indexing only), __launch_bounds__(192,3) to allow ~170
// VGPRs (3 waves/SIMD kept). >=16-32 loads in flight per wave at all times.
// Fragment mappings per verified m89/m91/m97 chain (16x16x32_bf16):
//   A[m=lane&15][k=(lane>>4)*8+j], B[k=(lane>>4)*8+j][n=lane&15],
//   C/D: col=lane&15, row=(lane>>4)*4+reg.

#define ND 32
#define NPAIR 6
#define SPB 32                  // samples per block
#define BT 192                  // 3 waves
#define OSTR 200                // obuf dword stride per sample (192 + 8 pad)

typedef __attribute__((ext_vector_type(8))) short bf16x8;
typedef __attribute__((ext_vector_type(4))) float f32x4;

union BU { unsigned u[4]; bf16x8 v; };

// pack two fp32 -> two bf16 (truncate): low16 = bf16(lo), high16 = bf16(hi)
__device__ __forceinline__ unsigned pack2(float lo, float hi) {
    return __builtin_amdgcn_perm(__float_as_uint(hi), __float_as_uint(lo), 0x07060302u);
}

__global__ __launch_bounds__(BT, 3) void dijet_mfma(
    const float* __restrict__ x,    // [N, 32, 12]
    const float* __restrict__ d,    // [N, 32, 6]
    const float* __restrict__ W,    // [32, 32, 3]
    const float* __restrict__ bias, // [32]
    float* __restrict__ out,        // [N, 32, 6]
    int N)
{
    __shared__ __align__(16) float obuf[SPB * OSTR];   // 25600 B

    const int t    = threadIdx.x;
    const int n0   = blockIdx.x * SPB;
    const bool full = (n0 + SPB <= N);

    const int w     = t >> 6;
    const int l     = t & 63;
    const int row16 = l & 15;
    const int quad  = l >> 4;
    const int ct0   = w * 4;       // wave owns col-tiles ct0..ct0+3

    // ---- A fragments: direct gather from W (12 KB, L1/L2-resident) ----
    // Af[ot][ks] reg j' holds k = ks*32 + quad*8 + j'.
    // ks=0,1: c = 16*ks + quad*4 + (j'>>1), j = j'&1 -> W[o*96 + c*3 + j]
    // ks=2:   c = quad*8 + j', j = 2        -> W[o*96 + c*3 + 2]
    bf16x8 Af[2][3];
#pragma unroll
    for (int ot = 0; ot < 2; ++ot) {
        const float* wb = W + (ot * 16 + row16) * 96;
        const float* wq = wb + quad * 12;           // ks=0,1 base (c = quad*4)
#pragma unroll
        for (int ks = 0; ks < 2; ++ks) {
            BU b;
#pragma unroll
            for (int cc = 0; cc < 4; ++cc) {
                const float* p = wq + (16 * ks + cc) * 3;
                b.u[cc] = pack2(p[0], p[1]);
            }
            Af[ot][ks] = b.v;
        }
        const float* wq2 = wb + quad * 24 + 2;      // ks=2 base (c = quad*8)
        BU b2;
#pragma unroll
        for (int m = 0; m < 4; ++m)
            b2.u[m] = pack2(wq2[(2 * m) * 3], wq2[(2 * m + 1) * 3]);
        Af[ot][2] = b2.v;
    }

    // accumulators init with bias: reg r of (ct, ot) holds o = ot*16 + quad*4 + r
    float4 bv0 = *(const float4*)(bias + quad * 4);
    float4 bv1 = *(const float4*)(bias + 16 + quad * 4);
    f32x4 acc[4][2];
#pragma unroll
    for (int ct = 0; ct < 4; ++ct) {
        acc[ct][0] = (f32x4){bv0.x, bv0.y, bv0.z, bv0.w};
        acc[ct][1] = (f32x4){bv1.x, bv1.y, bv1.z, bv1.w};
    }

    // ---- B fragments: depth-2 pipelined gather over the 4 col-tiles ----
    // Named buffers, static indexing only (rule #20).
    float2 xa[8], xb[8];
    float  da[8], db[8];

    auto loadct = [&](int ct, float2* xv, float* dv) {
        const int col = (ct0 + ct) * 16 + row16;
        const int ls  = col / 6;
        const int s   = col - ls * 6;
        const bool ok = full || (n0 + ls < N);
        // x[n, c, e] at n*384 + c*12 + e ; need c = quad*4+cc (+16)
        const float* xp = x + (size_t)(n0 + ls) * 384 + quad * 48 + 2 * s;
        // d[n, c, s] at n*192 + c*6 + s ; need c = quad*8 + j'
        const float* dp = d + (size_t)(n0 + ls) * 192 + quad * 48 + s;
#pragma unroll
        for (int cc = 0; cc < 4; ++cc) {
            xv[cc]     = ok ? *(const float2*)(xp + cc * 12)       : make_float2(0.f, 0.f);
            xv[4 + cc] = ok ? *(const float2*)(xp + 192 + cc * 12) : make_float2(0.f, 0.f);
        }
#pragma unroll
        for (int j = 0; j < 8; ++j)
            dv[j] = ok ? dp[j * 6] : 0.f;
    };

    auto mfmact = [&](int ct, const float2* xv, const float* dv) {
        BU b0, b1, b2;
#pragma unroll
        for (int cc = 0; cc < 4; ++cc) {
            b0.u[cc] = pack2(xv[cc].x, xv[cc].y);
            b1.u[cc] = pack2(xv[4 + cc].x, xv[4 + cc].y);
        }
#pragma unroll
        for (int m = 0; m < 4; ++m)
            b2.u[m] = pack2(dv[2 * m], dv[2 * m + 1]);
        acc[ct][0] = __builtin_amdgcn_mfma_f32_16x16x32_bf16(Af[0][0], b0.v, acc[ct][0], 0, 0, 0);
        acc[ct][0] = __builtin_amdgcn_mfma_f32_16x16x32_bf16(Af[0][1], b1.v, acc[ct][0], 0, 0, 0);
        acc[ct][0] = __builtin_amdgcn_mfma_f32_16x16x32_bf16(Af[0][2], b2.v, acc[ct][0], 0, 0, 0);
        acc[ct][1] = __builtin_amdgcn_mfma_f32_16x16x32_bf16(Af[1][0], b0.v, acc[ct][1], 0, 0, 0);
        acc[ct][1] = __builtin_amdgcn_mfma_f32_16x16x32_bf16(Af[1][1], b1.v, acc[ct][1], 0, 0, 0);
        acc[ct][1] = __builtin_amdgcn_mfma_f32_16x16x32_bf16(Af[1][2], b2.v, acc[ct][1], 0, 0, 0);
    };

    // prologue: two tiles in flight
    loadct(0, xa, da);
    loadct(1, xb, db);
    // steady state: consume one, refill with tile+2
    mfmact(0, xa, da);  loadct(2, xa, da);
    mfmact(1, xb, db);  loadct(3, xb, db);
    mfmact(2, xa, da);
    mfmact(3, xb, db);

    // ---- epilogue: C/D -> padded LDS out-layout ----
#pragma unroll
    for (int ct = 0; ct < 4; ++ct) {
        const int col = (ct0 + ct) * 16 + row16;
        const int ls  = col / 6;
        const int s   = col - ls * 6;
        float* ob = obuf + ls * OSTR + s;
#pragma unroll
        for (int ot = 0; ot < 2; ++ot) {
            const int o0 = ot * 16 + quad * 4;
            ob[(o0 + 0) * NPAIR] = acc[ct][ot].x;
            ob[(o0 + 1) * NPAIR] = acc[ct][ot].y;
            ob[(o0 + 2) * NPAIR] = acc[ct][ot].z;
            ob[(o0 + 3) * NPAIR] = acc[ct][ot].w;
        }
    }

    __syncthreads();

    // ---- coalesced float4 writeback (proven in R2: exact-ideal WRITE_SIZE) ----
    float* og = out + (size_t)n0 * (ND * NPAIR);
#pragma unroll
    for (int k = 0; k < 8; ++k) {
        const int F  = 4 * (t + k * BT);     // [0, 6144)
        const int ns = F / 192;
        const int wi = F % 192;
        if (full || n0 + ns < N) {
            float4 v = *(const float4*)(obuf + ns * OSTR + wi);
            *(float4*)(og + ns * 192 + wi) = v;
        }
    }
}

extern "C" void kernel_launch(void* const* d_in, const int* in_sizes, int n_in,
                              void* d_out, int out_size, void* d_ws, size_t ws_size,
                              hipStream_t stream) {
    const float* x = (const float*)d_in[0];
    const float* d = (const float*)d_in[1];
    const float* W = (const float*)d_in[2];
    const float* b = (const float*)d_in[3];
    float* out = (float*)d_out;

    int N = in_sizes[0] / (ND * 2 * NPAIR);
    int blocks = (N + SPB - 1) / SPB;

    dijet_mfma<<<blocks, BT, 0, stream>>>(x, d, W, b, out, N);
}

// Round 3
// 383.034 us; speedup vs baseline: 1.0534x; 1.0534x over previous
//
#include <hip/hip_runtime.h>

// dijetReinforceLayer via MFMA, R5: direct gather, ALL B loads issued up
// front behind a sched_barrier(0) fence to force 64 loads in flight/wave.
// out[n,o,s] = b[o] + sum_{c,j} W[o,c,j] * din[n,c,s,j],
//   din[...,0..1] = x[n,c,2s..2s+1], din[...,2] = d[n,c,s].
// GEMM view: out[o, col] = sum_k A[o,k] B[k,col], col=(n,s), K=96.
// K reorder: k = 2c+j for j in {0,1} (x part), k = 64+c for j=2 (d part).
//
// R5 theory: R3/R4 both landed at VGPR=64 -- the compiler folded the
// pipeline buffers and re-serialized loads next to uses (~0.4 loads in
// flight/wave by Little's law at 1.7 TB/s). The cache-hot rocprof replay
// (FETCH~2MB) ran at the SAME 155us => latency-exposure wall, not BW.
// Fix: issue all 64 B-fragment loads (24.5 KB/lane-wave) into named
// statically-indexed register buffers, then __builtin_amdgcn_sched_barrier(0)
// so no load can sink past it; consume in issue order so the compiler emits
// counted vmcnt(48/32/16/0). Proof-of-honor metric: VGPR must jump >>64.
// Fragment mappings per verified m89/m91/m97 chain (16x16x32_bf16):
//   A[m=lane&15][k=(lane>>4)*8+j], B[k=(lane>>4)*8+j][n=lane&15],
//   C/D: col=lane&15, row=(lane>>4)*4+reg.

#define ND 32
#define NPAIR 6
#define SPB 32                  // samples per block
#define BT 192                  // 3 waves
#define OSTR 200                // obuf dword stride per sample (192 + 8 pad)

typedef __attribute__((ext_vector_type(8))) short bf16x8;
typedef __attribute__((ext_vector_type(4))) float f32x4;

union BU { unsigned u[4]; bf16x8 v; };

// pack two fp32 -> two bf16 (truncate): low16 = bf16(lo), high16 = bf16(hi)
__device__ __forceinline__ unsigned pack2(float lo, float hi) {
    return __builtin_amdgcn_perm(__float_as_uint(hi), __float_as_uint(lo), 0x07060302u);
}

__global__ __launch_bounds__(BT) void dijet_mfma(
    const float* __restrict__ x,    // [N, 32, 12]
    const float* __restrict__ d,    // [N, 32, 6]
    const float* __restrict__ W,    // [32, 32, 3]
    const float* __restrict__ bias, // [32]
    float* __restrict__ out,        // [N, 32, 6]
    int N)
{
    __shared__ __align__(16) float obuf[SPB * OSTR];   // 25600 B

    const int t    = threadIdx.x;
    const int n0   = blockIdx.x * SPB;
    const bool full = (n0 + SPB <= N);

    const int w     = t >> 6;
    const int l     = t & 63;
    const int row16 = l & 15;
    const int quad  = l >> 4;
    const int ct0   = w * 4;       // wave owns col-tiles ct0..ct0+3

    // ---- A fragments: direct gather from W (12 KB, L1/L2-resident) ----
    // Af[ot][ks] reg j' holds k = ks*32 + quad*8 + j'.
    // ks=0,1: c = 16*ks + quad*4 + (j'>>1), j = j'&1 -> W[o*96 + c*3 + j]
    // ks=2:   c = quad*8 + j', j = 2        -> W[o*96 + c*3 + 2]
    bf16x8 Af[2][3];
#pragma unroll
    for (int ot = 0; ot < 2; ++ot) {
        const float* wb = W + (ot * 16 + row16) * 96;
        const float* wq = wb + quad * 12;           // ks=0,1 base (c = quad*4)
#pragma unroll
        for (int ks = 0; ks < 2; ++ks) {
            BU b;
#pragma unroll
            for (int cc = 0; cc < 4; ++cc) {
                const float* p = wq + (16 * ks + cc) * 3;
                b.u[cc] = pack2(p[0], p[1]);
            }
            Af[ot][ks] = b.v;
        }
        const float* wq2 = wb + quad * 24 + 2;      // ks=2 base (c = quad*8)
        BU b2;
#pragma unroll
        for (int m = 0; m < 4; ++m)
            b2.u[m] = pack2(wq2[(2 * m) * 3], wq2[(2 * m + 1) * 3]);
        Af[ot][2] = b2.v;
    }

    // accumulators init with bias: reg r of (ct, ot) holds o = ot*16 + quad*4 + r
    float4 bv0 = *(const float4*)(bias + quad * 4);
    float4 bv1 = *(const float4*)(bias + 16 + quad * 4);
    f32x4 acc[4][2];
#pragma unroll
    for (int ct = 0; ct < 4; ++ct) {
        acc[ct][0] = (f32x4){bv0.x, bv0.y, bv0.z, bv0.w};
        acc[ct][1] = (f32x4){bv1.x, bv1.y, bv1.z, bv1.w};
    }

    // ---- B fragments: issue ALL 64 loads (4 col-tiles) before any use ----
    float2 xv[4][8];   // [ct][cc:0-3 = B0 pairs, 4-7 = B1 pairs]
    float  dv[4][8];   // [ct][j]
#pragma unroll
    for (int ct = 0; ct < 4; ++ct) {
        const int col = (ct0 + ct) * 16 + row16;
        const int ls  = col / 6;
        const int s   = col - ls * 6;
        const bool ok = full || (n0 + ls < N);
        // x[n, c, e] at n*384 + c*12 + e ; need c = quad*4+cc (+16)
        const float* xp = x + (size_t)(n0 + ls) * 384 + quad * 48 + 2 * s;
        // d[n, c, s] at n*192 + c*6 + s ; need c = quad*8 + j'
        const float* dp = d + (size_t)(n0 + ls) * 192 + quad * 48 + s;
#pragma unroll
        for (int cc = 0; cc < 4; ++cc) {
            xv[ct][cc]     = ok ? *(const float2*)(xp + cc * 12)       : make_float2(0.f, 0.f);
            xv[ct][4 + cc] = ok ? *(const float2*)(xp + 192 + cc * 12) : make_float2(0.f, 0.f);
        }
#pragma unroll
        for (int j = 0; j < 8; ++j)
            dv[ct][j] = ok ? dp[j * 6] : 0.f;
    }

    // Fence: no load above may sink below; consume in issue order so the
    // compiler emits progressive counted vmcnt waits (48/32/16/0).
    __builtin_amdgcn_sched_barrier(0);

#pragma unroll
    for (int ct = 0; ct < 4; ++ct) {
        BU b0, b1, b2;
#pragma unroll
        for (int cc = 0; cc < 4; ++cc) {
            b0.u[cc] = pack2(xv[ct][cc].x,     xv[ct][cc].y);
            b1.u[cc] = pack2(xv[ct][4 + cc].x, xv[ct][4 + cc].y);
        }
#pragma unroll
        for (int m = 0; m < 4; ++m)
            b2.u[m] = pack2(dv[ct][2 * m], dv[ct][2 * m + 1]);
        acc[ct][0] = __builtin_amdgcn_mfma_f32_16x16x32_bf16(Af[0][0], b0.v, acc[ct][0], 0, 0, 0);
        acc[ct][0] = __builtin_amdgcn_mfma_f32_16x16x32_bf16(Af[0][1], b1.v, acc[ct][0], 0, 0, 0);
        acc[ct][0] = __builtin_amdgcn_mfma_f32_16x16x32_bf16(Af[0][2], b2.v, acc[ct][0], 0, 0, 0);
        acc[ct][1] = __builtin_amdgcn_mfma_f32_16x16x32_bf16(Af[1][0], b0.v, acc[ct][1], 0, 0, 0);
        acc[ct][1] = __builtin_amdgcn_mfma_f32_16x16x32_bf16(Af[1][1], b1.v, acc[ct][1], 0, 0, 0);
        acc[ct][1] = __builtin_amdgcn_mfma_f32_16x16x32_bf16(Af[1][2], b2.v, acc[ct][1], 0, 0, 0);
    }

    // ---- epilogue: C/D -> padded LDS out-layout ----
#pragma unroll
    for (int ct = 0; ct < 4; ++ct) {
        const int col = (ct0 + ct) * 16 + row16;
        const int ls  = col / 6;
        const int s   = col - ls * 6;
        float* ob = obuf + ls * OSTR + s;
#pragma unroll
        for (int ot = 0; ot < 2; ++ot) {
            const int o0 = ot * 16 + quad * 4;
            ob[(o0 + 0) * NPAIR] = acc[ct][ot].x;
            ob[(o0 + 1) * NPAIR] = acc[ct][ot].y;
            ob[(o0 + 2) * NPAIR] = acc[ct][ot].z;
            ob[(o0 + 3) * NPAIR] = acc[ct][ot].w;
        }
    }

    __syncthreads();

    // ---- coalesced float4 writeback (proven in R2: exact-ideal WRITE_SIZE) ----
    float* og = out + (size_t)n0 * (ND * NPAIR);
#pragma unroll
    for (int k = 0; k < 8; ++k) {
        const int F  = 4 * (t + k * BT);     // [0, 6144)
        const int ns = F / 192;
        const int wi = F % 192;
        if (full || n0 + ns < N) {
            float4 v = *(const float4*)(obuf + ns * OSTR + wi);
            *(float4*)(og + ns * 192 + wi) = v;
        }
    }
}

extern "C" void kernel_launch(void* const* d_in, const int* in_sizes, int n_in,
                              void* d_out, int out_size, void* d_ws, size_t ws_size,
                              hipStream_t stream) {
    const float* x = (const float*)d_in[0];
    const float* d = (const float*)d_in[1];
    const float* W = (const float*)d_in[2];
    const float* b = (const float*)d_in[3];
    float* out = (float*)d_out;

    int N = in_sizes[0] / (ND * 2 * NPAIR);
    int blocks = (N + SPB - 1) / SPB;

    dijet_mfma<<<blocks, BT, 0, stream>>>(x, d, W, b, out, N);
}

// Round 4
// 362.407 us; speedup vs baseline: 1.1134x; 1.0569x over previous
//
#include <hip/hip_runtime.h>

// dijetReinforceLayer via MFMA, R6: all-coalesced VMEM.
// out[n,o,s] = b[o] + sum_{c,j} W[o,c,j] * din[n,c,s,j],
//   din[...,0..1] = x[n,c,2s..2s+1], din[...,2] = d[n,c,s].
// GEMM view: out[o, col] = sum_k A[o,k] B[k,col], col=(n,s), K=96.
// K reorder: k = 2c+j for j in {0,1} (x part), k = 64+c for j=2 (d part).
//
// R6 theory: R5 proved the wall is scattered-VMEM processing throughput:
// ~100 VMEM insts/wave x 64 distinct lines each ~= 64 cyc/inst in TA/L1
// -> 307K cyc/CU ~= the measured 138us, and the cache-hot replay ran at the
// SAME time (hit or miss, scatter costs the same TA processing).
// Fix: (1) B-operand: stage raw x+d into LDS with global_load_lds dwordx4
// (24 coalesced 1KB wave-insts vs ~64 scattered); per-lane scatter moves to
// LDS (ds_read_b64/b32, ~5-way bank aliasing tolerated, LDS not critical).
// (2) A-operand: one-time prep kernel packs lane-ordered bf16 A-fragments
// (6 KB) into d_ws; main kernel loads them with 6 coalesced 16B/lane insts.
// -> kernel becomes HBM-bound: ~252 MB @ 5-6 TB/s => ~45-55us/dispatch.
// Fragment mappings per verified m89/m91/m97 chain (16x16x32_bf16):
//   A[m=lane&15][k=(lane>>4)*8+j], B[k=(lane>>4)*8+j][n=lane&15],
//   C/D: col=lane&15, row=(lane>>4)*4+reg.

#define ND 32
#define NPAIR 6
#define SPB 32                  // samples per block
#define BT 192                  // 3 waves
#define OSTR 200                // obuf dword stride per sample (192 + 8 pad)
#define XBYTES (SPB * 1536)     // 49152 B staged x
#define DBYTES (SPB * 768)      // 24576 B staged d

typedef __attribute__((ext_vector_type(8))) short bf16x8;
typedef __attribute__((ext_vector_type(4))) float f32x4;
typedef unsigned int u32;

union BU { unsigned u[4]; bf16x8 v; };

// pack two fp32 -> two bf16 (truncate): low16 = bf16(lo), high16 = bf16(hi)
__device__ __forceinline__ unsigned pack2(float lo, float hi) {
    return __builtin_amdgcn_perm(__float_as_uint(hi), __float_as_uint(lo), 0x07060302u);
}
__device__ __forceinline__ unsigned short bf16t(float v) {
    return (unsigned short)(__float_as_uint(v) >> 16);
}

__device__ __forceinline__ void load_lds16(const void* g, void* l) {
    __builtin_amdgcn_global_load_lds(
        (const __attribute__((address_space(1))) u32*)g,
        (__attribute__((address_space(3))) u32*)l, 16, 0, 0);
}

// ---- prep: pack A-fragments (lane-ordered bf16) into workspace ----
// ws[f*64 + l] (16 B each), f = ot*3+ks. Same gather math as R5 (verified).
__global__ void dijet_prep(const float* __restrict__ W, uint4* __restrict__ ws) {
    const int i = threadIdx.x;       // 384 threads: f = i>>6, l = i&63
    const int f = i >> 6;
    const int l = i & 63;
    const int row16 = l & 15;
    const int quad  = l >> 4;
    const int ot = f / 3, ks = f % 3;
    const float* wb = W + (ot * 16 + row16) * 96;
    BU b;
    if (ks < 2) {
        const float* wq = wb + quad * 12;            // c = quad*4 (+16ks+cc)
#pragma unroll
        for (int cc = 0; cc < 4; ++cc) {
            const float* p = wq + (16 * ks + cc) * 3;
            b.u[cc] = pack2(p[0], p[1]);
        }
    } else {
        const float* wq2 = wb + quad * 24 + 2;       // c = quad*8 + j', j = 2
#pragma unroll
        for (int m = 0; m < 4; ++m)
            b.u[m] = pack2(wq2[(2 * m) * 3], wq2[(2 * m + 1) * 3]);
    }
    ws[f * 64 + l] = *(const uint4*)&b;
}

__global__ __launch_bounds__(BT) void dijet_mfma(
    const float* __restrict__ x,    // [N, 32, 12]
    const float* __restrict__ d,    // [N, 32, 6]
    const uint4* __restrict__ ws,   // [6*64] packed A-fragments
    const float* __restrict__ bias, // [32]
    float* __restrict__ out,        // [N, 32, 6]
    int N)
{
    // x raw (48K) + d raw (24K); obuf (25.6K) overlays the x region later.
    __shared__ __align__(16) unsigned char smem[XBYTES + DBYTES];   // 73728 B

    const int t    = threadIdx.x;
    const int n0   = blockIdx.x * SPB;
    const bool full = (n0 + SPB <= N);

    const int wv    = t >> 6;
    const int l     = t & 63;
    const int row16 = l & 15;
    const int quad  = l >> 4;
    const int ct0   = wv * 4;      // wave owns col-tiles ct0..ct0+3

    // ---- stage x: 48 chunks of 1024 B, 16 per wave, coalesced direct-to-LDS
    {
        const size_t xmax = (size_t)N * 1536 - 1024;
#pragma unroll
        for (int i = 0; i < 16; ++i) {
            const int ci = i * 3 + wv;
            size_t goff = (size_t)n0 * 1536 + (size_t)ci * 1024;
            if (!full && goff > xmax) goff = xmax;   // clamp: garbage but safe
            load_lds16((const char*)x + goff + l * 16, smem + ci * 1024);
        }
    }
    // ---- stage d: 24 chunks of 1024 B, 8 per wave
    {
        const size_t dmax = (size_t)N * 768 - 1024;
#pragma unroll
        for (int i = 0; i < 8; ++i) {
            const int ci = i * 3 + wv;
            size_t goff = (size_t)n0 * 768 + (size_t)ci * 1024;
            if (!full && goff > dmax) goff = dmax;
            load_lds16((const char*)d + goff + l * 16, smem + XBYTES + ci * 1024);
        }
    }

    // ---- A fragments: 6 coalesced 16B/lane loads from prepacked ws ----
    bf16x8 Af[2][3];
#pragma unroll
    for (int ot = 0; ot < 2; ++ot)
#pragma unroll
        for (int ks = 0; ks < 3; ++ks) {
            uint4 r = ws[(ot * 3 + ks) * 64 + l];
            Af[ot][ks] = *(const bf16x8*)&r;
        }

    // accumulators init with bias: reg r of (ct, ot) holds o = ot*16 + quad*4 + r
    float4 bv0 = *(const float4*)(bias + quad * 4);
    float4 bv1 = *(const float4*)(bias + 16 + quad * 4);
    f32x4 acc[4][2];
#pragma unroll
    for (int ct = 0; ct < 4; ++ct) {
        acc[ct][0] = (f32x4){bv0.x, bv0.y, bv0.z, bv0.w};
        acc[ct][1] = (f32x4){bv1.x, bv1.y, bv1.z, bv1.w};
    }

    __syncthreads();   // staging complete (drains vmcnt)

    // ---- B fragments: gather from LDS, pack, MFMA ----
    const float* xls = (const float*)smem;            // [SPB][384]
    const float* dls = (const float*)(smem + XBYTES); // [SPB][192]
#pragma unroll
    for (int ct = 0; ct < 4; ++ct) {
        const int col = (ct0 + ct) * 16 + row16;
        const int ls  = col / 6;
        const int s   = col - ls * 6;
        const float* xp = xls + ls * 384 + quad * 48 + 2 * s;
        const float* dp = dls + ls * 192 + quad * 48 + s;

        float2 v0[4], v1[4];
        float  vd[8];
#pragma unroll
        for (int cc = 0; cc < 4; ++cc) {
            v0[cc] = *(const float2*)(xp + cc * 12);
            v1[cc] = *(const float2*)(xp + 192 + cc * 12);
        }
#pragma unroll
        for (int j = 0; j < 8; ++j)
            vd[j] = dp[j * 6];

        BU b0, b1, b2;
#pragma unroll
        for (int cc = 0; cc < 4; ++cc) {
            b0.u[cc] = pack2(v0[cc].x, v0[cc].y);
            b1.u[cc] = pack2(v1[cc].x, v1[cc].y);
        }
#pragma unroll
        for (int m = 0; m < 4; ++m)
            b2.u[m] = pack2(vd[2 * m], vd[2 * m + 1]);

        acc[ct][0] = __builtin_amdgcn_mfma_f32_16x16x32_bf16(Af[0][0], b0.v, acc[ct][0], 0, 0, 0);
        acc[ct][0] = __builtin_amdgcn_mfma_f32_16x16x32_bf16(Af[0][1], b1.v, acc[ct][0], 0, 0, 0);
        acc[ct][0] = __builtin_amdgcn_mfma_f32_16x16x32_bf16(Af[0][2], b2.v, acc[ct][0], 0, 0, 0);
        acc[ct][1] = __builtin_amdgcn_mfma_f32_16x16x32_bf16(Af[1][0], b0.v, acc[ct][1], 0, 0, 0);
        acc[ct][1] = __builtin_amdgcn_mfma_f32_16x16x32_bf16(Af[1][1], b1.v, acc[ct][1], 0, 0, 0);
        acc[ct][1] = __builtin_amdgcn_mfma_f32_16x16x32_bf16(Af[1][2], b2.v, acc[ct][1], 0, 0, 0);
    }

    __syncthreads();   // all B reads done; safe to overwrite x region with obuf

    // ---- epilogue: C/D -> padded LDS out-layout ----
    float* obuf = (float*)smem;
#pragma unroll
    for (int ct = 0; ct < 4; ++ct) {
        const int col = (ct0 + ct) * 16 + row16;
        const int ls  = col / 6;
        const int s   = col - ls * 6;
        float* ob = obuf + ls * OSTR + s;
#pragma unroll
        for (int ot = 0; ot < 2; ++ot) {
            const int o0 = ot * 16 + quad * 4;
            ob[(o0 + 0) * NPAIR] = acc[ct][ot].x;
            ob[(o0 + 1) * NPAIR] = acc[ct][ot].y;
            ob[(o0 + 2) * NPAIR] = acc[ct][ot].z;
            ob[(o0 + 3) * NPAIR] = acc[ct][ot].w;
        }
    }

    __syncthreads();

    // ---- coalesced float4 writeback (proven in R2: exact-ideal WRITE_SIZE) ----
    float* og = out + (size_t)n0 * (ND * NPAIR);
#pragma unroll
    for (int k = 0; k < 8; ++k) {
        const int F  = 4 * (t + k * BT);     // [0, 6144)
        const int ns = F / 192;
        const int wi = F % 192;
        if (full || n0 + ns < N) {
            float4 v = *(const float4*)(obuf + ns * OSTR + wi);
            *(float4*)(og + ns * 192 + wi) = v;
        }
    }
}

extern "C" void kernel_launch(void* const* d_in, const int* in_sizes, int n_in,
                              void* d_out, int out_size, void* d_ws, size_t ws_size,
                              hipStream_t stream) {
    const float* x = (const float*)d_in[0];
    const float* d = (const float*)d_in[1];
    const float* W = (const float*)d_in[2];
    const float* b = (const float*)d_in[3];
    float* out = (float*)d_out;

    int N = in_sizes[0] / (ND * 2 * NPAIR);
    int blocks = (N + SPB - 1) / SPB;

    dijet_prep<<<1, 384, 0, stream>>>(W, (uint4*)d_ws);
    dijet_mfma<<<blocks, BT, 0, stream>>>(x, d, (const uint4*)d_ws, b, out, N);
}